// Round 1
// baseline (225.041 us; speedup 1.0000x reference)
//
#include <hip/hip_runtime.h>

// ---------------------------------------------------------------------------
// MultilevelSelfAttentionBlockWithRoPE on MI355X (gfx950)
// Pipeline: LN -> (W transpose->bf16) -> QKV GEMM (bf16 MFMA) -> RoPE (in
// place) -> flash attention per (batch,head) -> out GEMM + residual.
// Workspace: ~58.7 MB.  All lengths are multiples of 64 (tail masks kept for
// safety anyway).
// ---------------------------------------------------------------------------

typedef float  f32x4  __attribute__((ext_vector_type(4)));
typedef __bf16 bf16x8 __attribute__((ext_vector_type(8)));
typedef short  s16x4  __attribute__((ext_vector_type(4)));
typedef short  s16x8  __attribute__((ext_vector_type(8)));
typedef unsigned short u16x4 __attribute__((ext_vector_type(4)));

typedef __attribute__((address_space(1))) void as1_void_t;
typedef __attribute__((address_space(3))) void as3_void_t;

static __device__ __forceinline__ unsigned short f2bf(float f) {
  unsigned int u = __float_as_uint(f);
  u += 0x7fffu + ((u >> 16) & 1u);          // round-to-nearest-even
  return (unsigned short)(u >> 16);
}
static __device__ __forceinline__ float bf2f(unsigned short s) {
  return __uint_as_float(((unsigned int)s) << 16);
}

static __device__ __forceinline__ void gload_lds16(const void* g, void* l) {
  // global -> LDS direct, 16B per lane; LDS dest = wave-uniform base + lane*16
  __builtin_amdgcn_global_load_lds((as1_void_t*)g, (as3_void_t*)l, 16, 0, 0);
}

static __device__ __forceinline__ f32x4 mfma32(bf16x8 a, bf16x8 b, f32x4 c) {
  return __builtin_amdgcn_mfma_f32_16x16x32_bf16(a, b, c, 0, 0, 0);
}
static __device__ __forceinline__ f32x4 mfma16(s16x4 a, s16x4 b, f32x4 c) {
  return __builtin_amdgcn_mfma_f32_16x16x16bf16_1k(a, b, c, 0, 0, 0);
}

// ---------------------------------------------------------------------------
// LayerNorm: x f32 [N][1024] -> h bf16 [N][1024].  One wave per row.
// ---------------------------------------------------------------------------
__global__ __launch_bounds__(256) void ln_kernel(
    const float* __restrict__ x, const float* __restrict__ gamma,
    const float* __restrict__ beta, unsigned short* __restrict__ h, int Ntok) {
  int row  = blockIdx.x * 4 + (threadIdx.x >> 6);
  int lane = threadIdx.x & 63;
  const float* xr = x + (size_t)row * 1024;
  f32x4 v[4];
  float s = 0.f, ss = 0.f;
#pragma unroll
  for (int c = 0; c < 4; ++c) {
    v[c] = *(const f32x4*)(xr + c * 256 + lane * 4);
#pragma unroll
    for (int j = 0; j < 4; ++j) { s += v[c][j]; ss += v[c][j] * v[c][j]; }
  }
#pragma unroll
  for (int d = 1; d < 64; d <<= 1) {
    s  += __shfl_xor(s, d);
    ss += __shfl_xor(ss, d);
  }
  float mu  = s * (1.f / 1024.f);
  float var = ss * (1.f / 1024.f) - mu * mu;
  float inv = rsqrtf(var + 1e-5f);
#pragma unroll
  for (int c = 0; c < 4; ++c) {
    f32x4 gv = *(const f32x4*)(gamma + c * 256 + lane * 4);
    f32x4 bv = *(const f32x4*)(beta  + c * 256 + lane * 4);
    u16x4 hv;
#pragma unroll
    for (int j = 0; j < 4; ++j) hv[j] = f2bf((v[c][j] - mu) * inv * gv[j] + bv[j]);
    *(u16x4*)(h + (size_t)row * 1024 + c * 256 + lane * 4) = hv;
  }
}

// ---------------------------------------------------------------------------
// Transpose+convert: in f32 [R][C] -> out bf16 [C][R]
// ---------------------------------------------------------------------------
__global__ __launch_bounds__(256) void transpose_bf16(
    const float* __restrict__ in, unsigned short* __restrict__ out, int R, int C) {
  __shared__ unsigned short tile[64][65];
  int c0 = blockIdx.x * 64, r0 = blockIdx.y * 64;
  int t = threadIdx.x;
  int tr = t >> 6, tc = t & 63;
#pragma unroll
  for (int i = 0; i < 16; ++i) {
    int rr = i * 4 + tr;
    tile[tc][rr] = f2bf(in[(size_t)(r0 + rr) * C + c0 + tc]);
  }
  __syncthreads();
#pragma unroll
  for (int i = 0; i < 16; ++i) {
    int cc = i * 4 + tr;
    out[(size_t)(c0 + cc) * R + r0 + tc] = tile[cc][tc];
  }
}

// ---------------------------------------------------------------------------
// GEMM  C[M][Ncols] = A[M][K](bf16) * Bt[Ncols][K](bf16)^T
// MODE 0: Cf = acc + residual (f32 out)
// MODE 1: scatter bf16 into QKV planes [3][16][M][64]  (col -> which,h,d)
// m97 structure: 128x128 tile, BK=32, 4 waves (2x2), global_load_lds(16B).
// ---------------------------------------------------------------------------
template <int MODE>
__global__ __launch_bounds__(256) void gemm_bt(
    const unsigned short* __restrict__ A, const unsigned short* __restrict__ Bt,
    const float* __restrict__ residual, float* __restrict__ Cf,
    unsigned short* __restrict__ Cqkv, int M, int Ncols, int K) {
  __shared__ unsigned short Alds[128 * 32];
  __shared__ unsigned short Blds[128 * 32];
  int n0 = blockIdx.x * 128, m0 = blockIdx.y * 128;
  int t = threadIdx.x, lane = t & 63, wave = t >> 6;
  int wr = wave >> 1, wc = wave & 1;
  int r = lane & 15, g = lane >> 4;
  f32x4 acc[4][4] = {};

  int srow = lane >> 2;          // 0..15
  int scol = (lane & 3) * 8;     // element offset: 0,8,16,24

  for (int k0 = 0; k0 < K; k0 += 32) {
    __syncthreads();
#pragma unroll
    for (int c = 0; c < 2; ++c) {
      int seg = wave * 2 + c;    // 0..7 -> 16 rows each
      gload_lds16(A  + (size_t)(m0 + seg * 16 + srow) * K + k0 + scol,
                  Alds + seg * 16 * 32);
      gload_lds16(Bt + (size_t)(n0 + seg * 16 + srow) * K + k0 + scol,
                  Blds + seg * 16 * 32);
    }
    __syncthreads();
    bf16x8 a[4], b[4];
#pragma unroll
    for (int m = 0; m < 4; ++m)
      a[m] = *(const bf16x8*)(Alds + (wr * 64 + m * 16 + r) * 32 + g * 8);
#pragma unroll
    for (int n = 0; n < 4; ++n)
      b[n] = *(const bf16x8*)(Blds + (wc * 64 + n * 16 + r) * 32 + g * 8);
#pragma unroll
    for (int m = 0; m < 4; ++m)
#pragma unroll
      for (int n = 0; n < 4; ++n)
        acc[m][n] = mfma32(a[m], b[n], acc[m][n]);
  }

#pragma unroll
  for (int mi = 0; mi < 4; ++mi) {
    int grow0 = m0 + wr * 64 + mi * 16 + g * 4;
#pragma unroll
    for (int ni = 0; ni < 4; ++ni) {
      int gcol = n0 + wc * 64 + ni * 16 + r;
      f32x4 v = acc[mi][ni];
#pragma unroll
      for (int e = 0; e < 4; ++e) {
        int grow = grow0 + e;
        if (MODE == 0) {
          Cf[(size_t)grow * Ncols + gcol] =
              v[e] + residual[(size_t)grow * Ncols + gcol];
        } else {
          int which = gcol >> 10, rem = gcol & 1023, hh = rem >> 6, d = rem & 63;
          Cqkv[((size_t)(which * 16 + hh) * M + grow) * 64 + d] = f2bf(v[e]);
        }
      }
    }
  }
}

// ---------------------------------------------------------------------------
// RoPE in place on Q,K planes of QKV [3][16][N][64] bf16.
// thread = (token i, head h, freq kk): rotate pair (2kk, 2kk+1).
// ---------------------------------------------------------------------------
__global__ __launch_bounds__(256) void rope_kernel(
    unsigned short* __restrict__ QKV, const float* __restrict__ pos,
    const float* __restrict__ freqs, int Ntok) {
  int t = blockIdx.x * 256 + threadIdx.x;
  if (t >= Ntok * 512) return;
  int kk = t & 31, h = (t >> 5) & 15, i = t >> 9;
  float lvlf = pos[i * 3 + 0];
  float py   = pos[i * 3 + 1];
  float px   = pos[i * 3 + 2];
  int lvl = (int)lvlf;
  lvl = lvl < 0 ? 0 : (lvl > 3 ? 3 : lvl);
  const float* fp = freqs + (((lvl * 16 + h) * 32 + kk) << 1);
  float ang = fp[0] * py + fp[1] * px;
  float s, c;
  __sincosf(ang, &s, &c);
  size_t qoff = ((size_t)h * Ntok + i) * 64 + 2 * kk;
  size_t koff = qoff + (size_t)16 * Ntok * 64;
  unsigned int q2 = *(const unsigned int*)(QKV + qoff);
  float qa = bf2f((unsigned short)(q2 & 0xffff));
  float qb = bf2f((unsigned short)(q2 >> 16));
  *(unsigned int*)(QKV + qoff) =
      (unsigned int)f2bf(qa * c - qb * s) | ((unsigned int)f2bf(qa * s + qb * c) << 16);
  unsigned int k2 = *(const unsigned int*)(QKV + koff);
  float ka = bf2f((unsigned short)(k2 & 0xffff));
  float kb = bf2f((unsigned short)(k2 >> 16));
  *(unsigned int*)(QKV + koff) =
      (unsigned int)f2bf(ka * c - kb * s) | ((unsigned int)f2bf(ka * s + kb * c) << 16);
}

// ---------------------------------------------------------------------------
// Flash attention per (batch, head, 64 q rows).  4 waves x 16 q rows.
// S^T = K*Q^T via mfma 16x16x32 (S^T C-frag == A-operand of 16x16x16 PV).
// K/V tiles of 64 keys staged in LDS (+8 pad per row vs bank conflicts).
// ---------------------------------------------------------------------------
__global__ __launch_bounds__(256) void attn_kernel(
    const unsigned short* __restrict__ QKV, const int* __restrict__ boff,
    unsigned short* __restrict__ O, int Ntok) {
  __shared__ unsigned short Klds[64][72];
  __shared__ unsigned short Vlds[64][72];
  int blk = blockIdx.x;
  int qblk = blk & 15, h = (blk >> 4) & 15, b = blk >> 8;
  int off = boff[b], len = boff[b + 1] - off;
  int q0 = qblk * 64;
  if (q0 >= len) return;
  int t = threadIdx.x, lane = t & 63, wave = t >> 6;
  int r = lane & 15, g = lane >> 4;
  const unsigned short* Qg = QKV + (size_t)h * Ntok * 64;
  const unsigned short* Kg = QKV + (size_t)(16 + h) * Ntok * 64;
  const unsigned short* Vg = QKV + (size_t)(32 + h) * Ntok * 64;

  int qmax = off + len - 1;
  int qtok = off + q0 + wave * 16 + r;
  if (qtok > qmax) qtok = qmax;
  bf16x8 qf0 = *(const bf16x8*)(Qg + (size_t)qtok * 64 + g * 8);
  bf16x8 qf1 = *(const bf16x8*)(Qg + (size_t)qtok * 64 + 32 + g * 8);

  float m = -1e30f, lsum = 0.f;
  f32x4 o[4] = {};

  for (int kt = 0; kt < len; kt += 64) {
    __syncthreads();
    {
      int row = t >> 2, seg = t & 3;
      int ktok = off + kt + row;
      if (ktok > qmax) ktok = qmax;
      const unsigned short* ks = Kg + (size_t)ktok * 64 + seg * 16;
      const unsigned short* vs = Vg + (size_t)ktok * 64 + seg * 16;
      *(s16x8*)&Klds[row][seg * 16]     = *(const s16x8*)ks;
      *(s16x8*)&Klds[row][seg * 16 + 8] = *(const s16x8*)(ks + 8);
      *(s16x8*)&Vlds[row][seg * 16]     = *(const s16x8*)vs;
      *(s16x8*)&Vlds[row][seg * 16 + 8] = *(const s16x8*)(vs + 8);
    }
    __syncthreads();
    bool tail = (kt + 64 > len);
#pragma unroll
    for (int sub = 0; sub < 4; ++sub) {
      bf16x8 ka0 = *(const bf16x8*)(&Klds[sub * 16 + r][g * 8]);
      bf16x8 ka1 = *(const bf16x8*)(&Klds[sub * 16 + r][32 + g * 8]);
      f32x4 s4 = {};
      s4 = mfma32(ka0, qf0, s4);
      s4 = mfma32(ka1, qf1, s4);
      // lane holds S^T[key = kt+sub*16+4g+e][q = q0+wave*16+r]
      float sc[4];
      bool msk[4];
      int kb = kt + sub * 16 + 4 * g;
#pragma unroll
      for (int e = 0; e < 4; ++e) {
        sc[e]  = s4[e] * 0.125f;
        msk[e] = tail && (kb + e >= len);
        if (msk[e]) sc[e] = -1e30f;
      }
      float tmax = fmaxf(fmaxf(sc[0], sc[1]), fmaxf(sc[2], sc[3]));
      tmax = fmaxf(tmax, __shfl_xor(tmax, 16));
      tmax = fmaxf(tmax, __shfl_xor(tmax, 32));
      float mnew  = fmaxf(m, tmax);
      float alpha = __expf(m - mnew);
      float p[4], psum = 0.f;
#pragma unroll
      for (int e = 0; e < 4; ++e) {
        p[e] = msk[e] ? 0.f : __expf(sc[e] - mnew);
        psum += p[e];
      }
      psum += __shfl_xor(psum, 16);
      psum += __shfl_xor(psum, 32);
      lsum = lsum * alpha + psum;
      m = mnew;
      s16x4 pf;
#pragma unroll
      for (int e = 0; e < 4; ++e) pf[e] = (short)f2bf(p[e]);
      float al[4];
#pragma unroll
      for (int e = 0; e < 4; ++e) al[e] = __shfl(alpha, 4 * g + e);
#pragma unroll
      for (int dt = 0; dt < 4; ++dt) {
        s16x4 vf;
#pragma unroll
        for (int e = 0; e < 4; ++e)
          vf[e] = (short)Vlds[sub * 16 + 4 * g + e][dt * 16 + r];
#pragma unroll
        for (int e = 0; e < 4; ++e) o[dt][e] *= al[e];
        o[dt] = mfma16(pf, vf, o[dt]);
      }
    }
  }
  float inv = 1.0f / lsum;
  float il[4];
#pragma unroll
  for (int e = 0; e < 4; ++e) il[e] = __shfl(inv, 4 * g + e);
#pragma unroll
  for (int dt = 0; dt < 4; ++dt)
#pragma unroll
    for (int e = 0; e < 4; ++e) {
      int tl = q0 + wave * 16 + 4 * g + e;
      if (tl < len)
        O[(size_t)(off + tl) * 1024 + h * 64 + dt * 16 + r] = f2bf(o[dt][e] * il[e]);
    }
}

// ---------------------------------------------------------------------------
extern "C" void kernel_launch(void* const* d_in, const int* in_sizes, int n_in,
                              void* d_out, int out_size, void* d_ws, size_t ws_size,
                              hipStream_t stream) {
  const float* x     = (const float*)d_in[0];
  const float* pos   = (const float*)d_in[1];
  const int*   boff  = (const int*)d_in[2];
  const float* gamma = (const float*)d_in[3];
  const float* beta  = (const float*)d_in[4];
  const float* wqkv  = (const float*)d_in[5];
  const float* wout  = (const float*)d_in[6];
  const float* freqs = (const float*)d_in[7];
  float* out = (float*)d_out;
  int N  = in_sizes[0] / 1024;   // 6144
  int Bn = in_sizes[2] - 1;      // 8

  char* ws = (char*)d_ws;
  unsigned short* wqkvT = (unsigned short*)ws;                           // 6.0 MiB
  unsigned short* woutT = (unsigned short*)(ws + (size_t)3072 * 1024 * 2);
  unsigned short* QKV   = (unsigned short*)(ws + (size_t)3072 * 1024 * 2 +
                                            (size_t)1024 * 1024 * 2);
  size_t qkvBytes = (size_t)48 * N * 64 * 2;                             // 36 MiB
  unsigned short* hbuf = (unsigned short*)((char*)QKV + qkvBytes);       // 12 MiB
  unsigned short* Obuf = hbuf;  // reuse: h is dead after the QKV GEMM

  ln_kernel<<<N / 4, 256, 0, stream>>>(x, gamma, beta, hbuf, N);
  transpose_bf16<<<dim3(3072 / 64, 1024 / 64), 256, 0, stream>>>(wqkv, wqkvT, 1024, 3072);
  transpose_bf16<<<dim3(1024 / 64, 1024 / 64), 256, 0, stream>>>(wout, woutT, 1024, 1024);
  gemm_bt<1><<<dim3(3072 / 128, N / 128), 256, 0, stream>>>(
      hbuf, wqkvT, nullptr, nullptr, QKV, N, 3072, 1024);
  rope_kernel<<<(N * 512) / 256, 256, 0, stream>>>(QKV, pos, freqs, N);
  attn_kernel<<<Bn * 16 * 16, 256, 0, stream>>>(QKV, boff, Obuf, N);
  gemm_bt<0><<<dim3(1024 / 128, N / 128), 256, 0, stream>>>(
      Obuf, woutT, x, out, nullptr, N, 1024, 1024);
}

// Round 2
// 207.594 us; speedup vs baseline: 1.0840x; 1.0840x over previous
//
#include <hip/hip_runtime.h>

// ---------------------------------------------------------------------------
// MultilevelSelfAttentionBlockWithRoPE on MI355X (gfx950)
// LN -> (W transpose->bf16) -> QKV GEMM (bf16 MFMA) -> RoPE -> flash
// attention per (batch,head,128-q-rows) -> out GEMM + residual.
// R2: attn rewritten — per-64-key softmax, transposed-V LDS (vector b64 PV
// reads), 32 q-rows/wave, reg-staged pipeline, defer-max, XCD swizzle.
// ---------------------------------------------------------------------------

typedef float  f32x4  __attribute__((ext_vector_type(4)));
typedef __bf16 bf16x8 __attribute__((ext_vector_type(8)));
typedef __bf16 bf16x4 __attribute__((ext_vector_type(4)));
typedef short  s16x4  __attribute__((ext_vector_type(4)));
typedef short  s16x8  __attribute__((ext_vector_type(8)));
typedef unsigned short u16x4 __attribute__((ext_vector_type(4)));

typedef __attribute__((address_space(1))) void as1_void_t;
typedef __attribute__((address_space(3))) void as3_void_t;

static __device__ __forceinline__ unsigned short f2bf(float f) {
  unsigned int u = __float_as_uint(f);
  u += 0x7fffu + ((u >> 16) & 1u);          // round-to-nearest-even
  return (unsigned short)(u >> 16);
}
static __device__ __forceinline__ float bf2f(unsigned short s) {
  return __uint_as_float(((unsigned int)s) << 16);
}

static __device__ __forceinline__ void gload_lds16(const void* g, void* l) {
  __builtin_amdgcn_global_load_lds((as1_void_t*)g, (as3_void_t*)l, 16, 0, 0);
}

static __device__ __forceinline__ f32x4 mfma32(bf16x8 a, bf16x8 b, f32x4 c) {
  return __builtin_amdgcn_mfma_f32_16x16x32_bf16(a, b, c, 0, 0, 0);
}
static __device__ __forceinline__ f32x4 mfma16(s16x4 a, s16x4 b, f32x4 c) {
  return __builtin_amdgcn_mfma_f32_16x16x16bf16_1k(a, b, c, 0, 0, 0);
}

// ---------------------------------------------------------------------------
// LayerNorm: x f32 [N][1024] -> h bf16 [N][1024].  One wave per row.
// ---------------------------------------------------------------------------
__global__ __launch_bounds__(256) void ln_kernel(
    const float* __restrict__ x, const float* __restrict__ gamma,
    const float* __restrict__ beta, unsigned short* __restrict__ h, int Ntok) {
  int row  = blockIdx.x * 4 + (threadIdx.x >> 6);
  int lane = threadIdx.x & 63;
  const float* xr = x + (size_t)row * 1024;
  f32x4 v[4];
  float s = 0.f, ss = 0.f;
#pragma unroll
  for (int c = 0; c < 4; ++c) {
    v[c] = *(const f32x4*)(xr + c * 256 + lane * 4);
#pragma unroll
    for (int j = 0; j < 4; ++j) { s += v[c][j]; ss += v[c][j] * v[c][j]; }
  }
#pragma unroll
  for (int d = 1; d < 64; d <<= 1) {
    s  += __shfl_xor(s, d);
    ss += __shfl_xor(ss, d);
  }
  float mu  = s * (1.f / 1024.f);
  float var = ss * (1.f / 1024.f) - mu * mu;
  float inv = rsqrtf(var + 1e-5f);
#pragma unroll
  for (int c = 0; c < 4; ++c) {
    f32x4 gv = *(const f32x4*)(gamma + c * 256 + lane * 4);
    f32x4 bv = *(const f32x4*)(beta  + c * 256 + lane * 4);
    u16x4 hv;
#pragma unroll
    for (int j = 0; j < 4; ++j) hv[j] = f2bf((v[c][j] - mu) * inv * gv[j] + bv[j]);
    *(u16x4*)(h + (size_t)row * 1024 + c * 256 + lane * 4) = hv;
  }
}

// ---------------------------------------------------------------------------
// Transpose+convert: in f32 [R][C] -> out bf16 [C][R]
// ---------------------------------------------------------------------------
__global__ __launch_bounds__(256) void transpose_bf16(
    const float* __restrict__ in, unsigned short* __restrict__ out, int R, int C) {
  __shared__ unsigned short tile[64][65];
  int c0 = blockIdx.x * 64, r0 = blockIdx.y * 64;
  int t = threadIdx.x;
  int tr = t >> 6, tc = t & 63;
#pragma unroll
  for (int i = 0; i < 16; ++i) {
    int rr = i * 4 + tr;
    tile[tc][rr] = f2bf(in[(size_t)(r0 + rr) * C + c0 + tc]);
  }
  __syncthreads();
#pragma unroll
  for (int i = 0; i < 16; ++i) {
    int cc = i * 4 + tr;
    out[(size_t)(c0 + cc) * R + r0 + tc] = tile[cc][tc];
  }
}

// ---------------------------------------------------------------------------
// GEMM  C[M][Ncols] = A[M][K](bf16) * Bt[Ncols][K](bf16)^T
// MODE 0: Cf = acc + residual (f32 out)
// MODE 1: scatter bf16 into QKV planes [3][16][M][64]
// ---------------------------------------------------------------------------
template <int MODE>
__global__ __launch_bounds__(256) void gemm_bt(
    const unsigned short* __restrict__ A, const unsigned short* __restrict__ Bt,
    const float* __restrict__ residual, float* __restrict__ Cf,
    unsigned short* __restrict__ Cqkv, int M, int Ncols, int K) {
  __shared__ unsigned short Alds[128 * 32];
  __shared__ unsigned short Blds[128 * 32];
  int n0 = blockIdx.x * 128, m0 = blockIdx.y * 128;
  int t = threadIdx.x, lane = t & 63, wave = t >> 6;
  int wr = wave >> 1, wc = wave & 1;
  int r = lane & 15, g = lane >> 4;
  f32x4 acc[4][4] = {};

  int srow = lane >> 2;
  int scol = (lane & 3) * 8;

  for (int k0 = 0; k0 < K; k0 += 32) {
    __syncthreads();
#pragma unroll
    for (int c = 0; c < 2; ++c) {
      int seg = wave * 2 + c;
      gload_lds16(A  + (size_t)(m0 + seg * 16 + srow) * K + k0 + scol,
                  Alds + seg * 16 * 32);
      gload_lds16(Bt + (size_t)(n0 + seg * 16 + srow) * K + k0 + scol,
                  Blds + seg * 16 * 32);
    }
    __syncthreads();
    bf16x8 a[4], b[4];
#pragma unroll
    for (int m = 0; m < 4; ++m)
      a[m] = *(const bf16x8*)(Alds + (wr * 64 + m * 16 + r) * 32 + g * 8);
#pragma unroll
    for (int n = 0; n < 4; ++n)
      b[n] = *(const bf16x8*)(Blds + (wc * 64 + n * 16 + r) * 32 + g * 8);
#pragma unroll
    for (int m = 0; m < 4; ++m)
#pragma unroll
      for (int n = 0; n < 4; ++n)
        acc[m][n] = mfma32(a[m], b[n], acc[m][n]);
  }

#pragma unroll
  for (int mi = 0; mi < 4; ++mi) {
    int grow0 = m0 + wr * 64 + mi * 16 + g * 4;
#pragma unroll
    for (int ni = 0; ni < 4; ++ni) {
      int gcol = n0 + wc * 64 + ni * 16 + r;
      f32x4 v = acc[mi][ni];
#pragma unroll
      for (int e = 0; e < 4; ++e) {
        int grow = grow0 + e;
        if (MODE == 0) {
          Cf[(size_t)grow * Ncols + gcol] =
              v[e] + residual[(size_t)grow * Ncols + gcol];
        } else {
          int which = gcol >> 10, rem = gcol & 1023, hh = rem >> 6, d = rem & 63;
          Cqkv[((size_t)(which * 16 + hh) * M + grow) * 64 + d] = f2bf(v[e]);
        }
      }
    }
  }
}

// ---------------------------------------------------------------------------
// RoPE in place on Q,K planes of QKV [3][16][N][64] bf16.
// ---------------------------------------------------------------------------
__global__ __launch_bounds__(256) void rope_kernel(
    unsigned short* __restrict__ QKV, const float* __restrict__ pos,
    const float* __restrict__ freqs, int Ntok) {
  int t = blockIdx.x * 256 + threadIdx.x;
  if (t >= Ntok * 512) return;
  int kk = t & 31, h = (t >> 5) & 15, i = t >> 9;
  float lvlf = pos[i * 3 + 0];
  float py   = pos[i * 3 + 1];
  float px   = pos[i * 3 + 2];
  int lvl = (int)lvlf;
  lvl = lvl < 0 ? 0 : (lvl > 3 ? 3 : lvl);
  const float* fp = freqs + (((lvl * 16 + h) * 32 + kk) << 1);
  float ang = fp[0] * py + fp[1] * px;
  float s, c;
  __sincosf(ang, &s, &c);
  size_t qoff = ((size_t)h * Ntok + i) * 64 + 2 * kk;
  size_t koff = qoff + (size_t)16 * Ntok * 64;
  unsigned int q2 = *(const unsigned int*)(QKV + qoff);
  float qa = bf2f((unsigned short)(q2 & 0xffff));
  float qb = bf2f((unsigned short)(q2 >> 16));
  *(unsigned int*)(QKV + qoff) =
      (unsigned int)f2bf(qa * c - qb * s) | ((unsigned int)f2bf(qa * s + qb * c) << 16);
  unsigned int k2 = *(const unsigned int*)(QKV + koff);
  float ka = bf2f((unsigned short)(k2 & 0xffff));
  float kb = bf2f((unsigned short)(k2 >> 16));
  *(unsigned int*)(QKV + koff) =
      (unsigned int)f2bf(ka * c - kb * s) | ((unsigned int)f2bf(ka * s + kb * c) << 16);
}

// ---------------------------------------------------------------------------
// Flash attention.  Block = (batch, head, 128 q rows); 4 waves x 32 q rows.
// S^T = K*Q^T (mfma 16x16x32); per-64-key-tile online softmax in log2 domain
// with defer-max; V stored transposed in LDS so PV B-frags are ds_read_b64;
// reg-staged single-LDS-buffer pipeline; XCD-aware block swizzle.
// ---------------------------------------------------------------------------
__global__ __launch_bounds__(256) void attn_kernel(
    const unsigned short* __restrict__ QKV, const int* __restrict__ boff,
    unsigned short* __restrict__ O, int Ntok) {
  __shared__ unsigned short Klds[64][72];
  __shared__ unsigned short Vt[64][72];   // Vt[d][key]
  const float SCALE_LOG2 = 0.125f * 1.44269504088896340736f;

  int nb  = gridDim.x;
  int bid = blockIdx.x;
  int cpx = nb >> 3;                       // nb % 8 == 0 (1024)
  int blk = (bid & 7) * cpx + (bid >> 3);  // XCD-contiguous work chunks
  int qblk = blk & 7, h = (blk >> 3) & 15, b = blk >> 7;
  int off = boff[b], len = boff[b + 1] - off;
  int q0 = qblk * 128;
  if (q0 >= len) return;
  int t = threadIdx.x, lane = t & 63, wave = t >> 6;
  int r = lane & 15, g = lane >> 4;
  const unsigned short* Qg = QKV + (size_t)h * Ntok * 64;
  const unsigned short* Kg = QKV + (size_t)(16 + h) * Ntok * 64;
  const unsigned short* Vg = QKV + (size_t)(32 + h) * Ntok * 64;
  int qmax = off + len - 1;

  bf16x8 qf[2][2];
#pragma unroll
  for (int qi = 0; qi < 2; ++qi) {
    int qtok = off + q0 + wave * 32 + qi * 16 + r;
    if (qtok > qmax) qtok = qmax;
#pragma unroll
    for (int c = 0; c < 2; ++c)
      qf[qi][c] = *(const bf16x8*)(Qg + (size_t)qtok * 64 + c * 32 + g * 8);
  }

  float m[2] = {-1e30f, -1e30f}, lsum[2] = {0.f, 0.f};
  f32x4 o[2][4] = {};

  // staging assignments
  int krow = t >> 2, kseg = t & 3;   // K: key=krow, d = kseg*16..+15
  int vp = t & 31, vdc = t >> 5;     // V: keys 2vp,2vp+1, d = vdc*8..+7

  s16x8 kr0, kr1, vr0, vr1;
  {
    int ktok = off + krow; if (ktok > qmax) ktok = qmax;
    kr0 = *(const s16x8*)(Kg + (size_t)ktok * 64 + kseg * 16);
    kr1 = *(const s16x8*)(Kg + (size_t)ktok * 64 + kseg * 16 + 8);
    int va = off + 2 * vp, vb = va + 1;
    if (va > qmax) va = qmax;
    if (vb > qmax) vb = qmax;
    vr0 = *(const s16x8*)(Vg + (size_t)va * 64 + vdc * 8);
    vr1 = *(const s16x8*)(Vg + (size_t)vb * 64 + vdc * 8);
  }

  for (int kt = 0; kt < len; kt += 64) {
    __syncthreads();                       // previous tile's compute done
    *(s16x8*)&Klds[krow][kseg * 16]     = kr0;
    *(s16x8*)&Klds[krow][kseg * 16 + 8] = kr1;
#pragma unroll
    for (int j = 0; j < 8; ++j) {
      unsigned int pk = (unsigned int)(unsigned short)vr0[j] |
                        ((unsigned int)(unsigned short)vr1[j] << 16);
      *(unsigned int*)&Vt[vdc * 8 + j][2 * vp] = pk;
    }
    int ktn = kt + 64;
    if (ktn < len) {                       // prefetch next tile into regs
      int ktok = off + ktn + krow; if (ktok > qmax) ktok = qmax;
      kr0 = *(const s16x8*)(Kg + (size_t)ktok * 64 + kseg * 16);
      kr1 = *(const s16x8*)(Kg + (size_t)ktok * 64 + kseg * 16 + 8);
      int va = off + ktn + 2 * vp, vb = va + 1;
      if (va > qmax) va = qmax;
      if (vb > qmax) vb = qmax;
      vr0 = *(const s16x8*)(Vg + (size_t)va * 64 + vdc * 8);
      vr1 = *(const s16x8*)(Vg + (size_t)vb * 64 + vdc * 8);
    }
    __syncthreads();                       // LDS tile ready

    // ---- scores: S^T[key][q] for 64 keys x 32 q rows -------------------
    f32x4 s[2][4];
#pragma unroll
    for (int sub = 0; sub < 4; ++sub) {
      bf16x8 ka0 = *(const bf16x8*)(&Klds[sub * 16 + r][g * 8]);
      bf16x8 ka1 = *(const bf16x8*)(&Klds[sub * 16 + r][32 + g * 8]);
#pragma unroll
      for (int qi = 0; qi < 2; ++qi) {
        f32x4 acc = {};
        acc = mfma32(ka0, qf[qi][0], acc);
        acc = mfma32(ka1, qf[qi][1], acc);
        s[qi][sub] = acc;
      }
    }

    bool tail = (kt + 64 > len);
    s16x4 pf[2][4];
#pragma unroll
    for (int qi = 0; qi < 2; ++qi) {
      float sc[4][4];
      float tmax = -1e30f;
#pragma unroll
      for (int sub = 0; sub < 4; ++sub)
#pragma unroll
        for (int e = 0; e < 4; ++e) {
          float v = s[qi][sub][e] * SCALE_LOG2;
          sc[sub][e] = v;
          tmax = fmaxf(tmax, v);
        }
      if (tail) {
#pragma unroll
        for (int sub = 0; sub < 4; ++sub)
#pragma unroll
          for (int e = 0; e < 4; ++e)
            if (kt + sub * 16 + 4 * g + e >= len) sc[sub][e] = -1e30f;
        tmax = -1e30f;
#pragma unroll
        for (int sub = 0; sub < 4; ++sub)
#pragma unroll
          for (int e = 0; e < 4; ++e) tmax = fmaxf(tmax, sc[sub][e]);
      }
      tmax = fmaxf(tmax, __shfl_xor(tmax, 16));
      tmax = fmaxf(tmax, __shfl_xor(tmax, 32));
      float mq = m[qi];
      if (!__all(tmax <= mq + 8.f)) {      // defer-max (log2 domain)
        float mnew = fmaxf(mq, tmax);
        float alpha = exp2f(mq - mnew);
        lsum[qi] *= alpha;
        m[qi] = mnew; mq = mnew;
        float al[4];
#pragma unroll
        for (int e = 0; e < 4; ++e) al[e] = __shfl(alpha, 4 * g + e);
#pragma unroll
        for (int dt = 0; dt < 4; ++dt)
#pragma unroll
          for (int e = 0; e < 4; ++e) o[qi][dt][e] *= al[e];
      }
      float psum = 0.f;
#pragma unroll
      for (int sub = 0; sub < 4; ++sub) {
        float p[4];
        bf16x4 pb;
#pragma unroll
        for (int e = 0; e < 4; ++e) {
          p[e] = exp2f(sc[sub][e] - mq);
          psum += p[e];
          pb[e] = (__bf16)p[e];
        }
        pf[qi][sub] = __builtin_bit_cast(s16x4, pb);
      }
      psum += __shfl_xor(psum, 16);
      psum += __shfl_xor(psum, 32);
      lsum[qi] += psum;
    }

    // ---- PV: O += P * V  (V^T frags are vector b64 reads) ---------------
#pragma unroll
    for (int dt = 0; dt < 4; ++dt)
#pragma unroll
      for (int sub = 0; sub < 4; ++sub) {
        s16x4 vf = *(const s16x4*)(&Vt[dt * 16 + r][sub * 16 + 4 * g]);
#pragma unroll
        for (int qi = 0; qi < 2; ++qi)
          o[qi][dt] = mfma16(pf[qi][sub], vf, o[qi][dt]);
      }
  }

#pragma unroll
  for (int qi = 0; qi < 2; ++qi) {
    float inv = 1.0f / lsum[qi];
    float il[4];
#pragma unroll
    for (int e = 0; e < 4; ++e) il[e] = __shfl(inv, 4 * g + e);
#pragma unroll
    for (int dt = 0; dt < 4; ++dt)
#pragma unroll
      for (int e = 0; e < 4; ++e) {
        int tl = q0 + wave * 32 + qi * 16 + 4 * g + e;
        if (tl < len)
          O[(size_t)(off + tl) * 1024 + h * 64 + dt * 16 + r] =
              f2bf(o[qi][dt][e] * il[e]);
      }
  }
}

// ---------------------------------------------------------------------------
extern "C" void kernel_launch(void* const* d_in, const int* in_sizes, int n_in,
                              void* d_out, int out_size, void* d_ws, size_t ws_size,
                              hipStream_t stream) {
  const float* x     = (const float*)d_in[0];
  const float* pos   = (const float*)d_in[1];
  const int*   boff  = (const int*)d_in[2];
  const float* gamma = (const float*)d_in[3];
  const float* beta  = (const float*)d_in[4];
  const float* wqkv  = (const float*)d_in[5];
  const float* wout  = (const float*)d_in[6];
  const float* freqs = (const float*)d_in[7];
  float* out = (float*)d_out;
  int N  = in_sizes[0] / 1024;   // 6144
  int Bn = in_sizes[2] - 1;      // 8

  char* ws = (char*)d_ws;
  unsigned short* wqkvT = (unsigned short*)ws;
  unsigned short* woutT = (unsigned short*)(ws + (size_t)3072 * 1024 * 2);
  unsigned short* QKV   = (unsigned short*)(ws + (size_t)3072 * 1024 * 2 +
                                            (size_t)1024 * 1024 * 2);
  size_t qkvBytes = (size_t)48 * N * 64 * 2;
  unsigned short* hbuf = (unsigned short*)((char*)QKV + qkvBytes);
  unsigned short* Obuf = hbuf;  // h is dead after the QKV GEMM

  ln_kernel<<<N / 4, 256, 0, stream>>>(x, gamma, beta, hbuf, N);
  transpose_bf16<<<dim3(3072 / 64, 1024 / 64), 256, 0, stream>>>(wqkv, wqkvT, 1024, 3072);
  transpose_bf16<<<dim3(1024 / 64, 1024 / 64), 256, 0, stream>>>(wout, woutT, 1024, 1024);
  gemm_bt<1><<<dim3(3072 / 128, N / 128), 256, 0, stream>>>(
      hbuf, wqkvT, nullptr, nullptr, QKV, N, 3072, 1024);
  rope_kernel<<<(N * 512) / 256, 256, 0, stream>>>(QKV, pos, freqs, N);
  attn_kernel<<<Bn * 16 * 8, 256, 0, stream>>>(QKV, boff, Obuf, N);
  gemm_bt<0><<<dim3(1024 / 128, N / 128), 256, 0, stream>>>(
      Obuf, woutT, x, out, nullptr, N, 1024, 1024);
}

// Round 3
// 201.588 us; speedup vs baseline: 1.1163x; 1.0298x over previous
//
#include <hip/hip_runtime.h>

// ---------------------------------------------------------------------------
// MultilevelSelfAttentionBlockWithRoPE on MI355X (gfx950)
// LN -> (W transpose->bf16) -> QKV GEMM (bf16 MFMA) -> RoPE -> flash
// attention -> out GEMM + residual.
// R3: attn blocks shrunk to 64 q-rows (4 waves x 16 q-rows) for 2x occupancy
// (784 -> 1536 blocks); latency-bound per R2 counters (occ 11.7%).
// ---------------------------------------------------------------------------

typedef float  f32x4  __attribute__((ext_vector_type(4)));
typedef __bf16 bf16x8 __attribute__((ext_vector_type(8)));
typedef __bf16 bf16x4 __attribute__((ext_vector_type(4)));
typedef short  s16x4  __attribute__((ext_vector_type(4)));
typedef short  s16x8  __attribute__((ext_vector_type(8)));
typedef unsigned short u16x4 __attribute__((ext_vector_type(4)));

typedef __attribute__((address_space(1))) void as1_void_t;
typedef __attribute__((address_space(3))) void as3_void_t;

static __device__ __forceinline__ unsigned short f2bf(float f) {
  unsigned int u = __float_as_uint(f);
  u += 0x7fffu + ((u >> 16) & 1u);          // round-to-nearest-even
  return (unsigned short)(u >> 16);
}
static __device__ __forceinline__ float bf2f(unsigned short s) {
  return __uint_as_float(((unsigned int)s) << 16);
}

static __device__ __forceinline__ void gload_lds16(const void* g, void* l) {
  __builtin_amdgcn_global_load_lds((as1_void_t*)g, (as3_void_t*)l, 16, 0, 0);
}

static __device__ __forceinline__ f32x4 mfma32(bf16x8 a, bf16x8 b, f32x4 c) {
  return __builtin_amdgcn_mfma_f32_16x16x32_bf16(a, b, c, 0, 0, 0);
}
static __device__ __forceinline__ f32x4 mfma16(s16x4 a, s16x4 b, f32x4 c) {
  return __builtin_amdgcn_mfma_f32_16x16x16bf16_1k(a, b, c, 0, 0, 0);
}

// ---------------------------------------------------------------------------
// LayerNorm: x f32 [N][1024] -> h bf16 [N][1024].  One wave per row.
// ---------------------------------------------------------------------------
__global__ __launch_bounds__(256) void ln_kernel(
    const float* __restrict__ x, const float* __restrict__ gamma,
    const float* __restrict__ beta, unsigned short* __restrict__ h, int Ntok) {
  int row  = blockIdx.x * 4 + (threadIdx.x >> 6);
  int lane = threadIdx.x & 63;
  const float* xr = x + (size_t)row * 1024;
  f32x4 v[4];
  float s = 0.f, ss = 0.f;
#pragma unroll
  for (int c = 0; c < 4; ++c) {
    v[c] = *(const f32x4*)(xr + c * 256 + lane * 4);
#pragma unroll
    for (int j = 0; j < 4; ++j) { s += v[c][j]; ss += v[c][j] * v[c][j]; }
  }
#pragma unroll
  for (int d = 1; d < 64; d <<= 1) {
    s  += __shfl_xor(s, d);
    ss += __shfl_xor(ss, d);
  }
  float mu  = s * (1.f / 1024.f);
  float var = ss * (1.f / 1024.f) - mu * mu;
  float inv = rsqrtf(var + 1e-5f);
#pragma unroll
  for (int c = 0; c < 4; ++c) {
    f32x4 gv = *(const f32x4*)(gamma + c * 256 + lane * 4);
    f32x4 bv = *(const f32x4*)(beta  + c * 256 + lane * 4);
    u16x4 hv;
#pragma unroll
    for (int j = 0; j < 4; ++j) hv[j] = f2bf((v[c][j] - mu) * inv * gv[j] + bv[j]);
    *(u16x4*)(h + (size_t)row * 1024 + c * 256 + lane * 4) = hv;
  }
}

// ---------------------------------------------------------------------------
// Transpose+convert: in f32 [R][C] -> out bf16 [C][R]
// ---------------------------------------------------------------------------
__global__ __launch_bounds__(256) void transpose_bf16(
    const float* __restrict__ in, unsigned short* __restrict__ out, int R, int C) {
  __shared__ unsigned short tile[64][65];
  int c0 = blockIdx.x * 64, r0 = blockIdx.y * 64;
  int t = threadIdx.x;
  int tr = t >> 6, tc = t & 63;
#pragma unroll
  for (int i = 0; i < 16; ++i) {
    int rr = i * 4 + tr;
    tile[tc][rr] = f2bf(in[(size_t)(r0 + rr) * C + c0 + tc]);
  }
  __syncthreads();
#pragma unroll
  for (int i = 0; i < 16; ++i) {
    int cc = i * 4 + tr;
    out[(size_t)(c0 + cc) * R + r0 + tc] = tile[cc][tc];
  }
}

// ---------------------------------------------------------------------------
// GEMM  C[M][Ncols] = A[M][K](bf16) * Bt[Ncols][K](bf16)^T
// MODE 0: Cf = acc + residual (f32 out)
// MODE 1: scatter bf16 into QKV planes [3][16][M][64]
// ---------------------------------------------------------------------------
template <int MODE>
__global__ __launch_bounds__(256) void gemm_bt(
    const unsigned short* __restrict__ A, const unsigned short* __restrict__ Bt,
    const float* __restrict__ residual, float* __restrict__ Cf,
    unsigned short* __restrict__ Cqkv, int M, int Ncols, int K) {
  __shared__ unsigned short Alds[128 * 32];
  __shared__ unsigned short Blds[128 * 32];
  int n0 = blockIdx.x * 128, m0 = blockIdx.y * 128;
  int t = threadIdx.x, lane = t & 63, wave = t >> 6;
  int wr = wave >> 1, wc = wave & 1;
  int r = lane & 15, g = lane >> 4;
  f32x4 acc[4][4] = {};

  int srow = lane >> 2;
  int scol = (lane & 3) * 8;

  for (int k0 = 0; k0 < K; k0 += 32) {
    __syncthreads();
#pragma unroll
    for (int c = 0; c < 2; ++c) {
      int seg = wave * 2 + c;
      gload_lds16(A  + (size_t)(m0 + seg * 16 + srow) * K + k0 + scol,
                  Alds + seg * 16 * 32);
      gload_lds16(Bt + (size_t)(n0 + seg * 16 + srow) * K + k0 + scol,
                  Blds + seg * 16 * 32);
    }
    __syncthreads();
    bf16x8 a[4], b[4];
#pragma unroll
    for (int m = 0; m < 4; ++m)
      a[m] = *(const bf16x8*)(Alds + (wr * 64 + m * 16 + r) * 32 + g * 8);
#pragma unroll
    for (int n = 0; n < 4; ++n)
      b[n] = *(const bf16x8*)(Blds + (wc * 64 + n * 16 + r) * 32 + g * 8);
#pragma unroll
    for (int m = 0; m < 4; ++m)
#pragma unroll
      for (int n = 0; n < 4; ++n)
        acc[m][n] = mfma32(a[m], b[n], acc[m][n]);
  }

#pragma unroll
  for (int mi = 0; mi < 4; ++mi) {
    int grow0 = m0 + wr * 64 + mi * 16 + g * 4;
#pragma unroll
    for (int ni = 0; ni < 4; ++ni) {
      int gcol = n0 + wc * 64 + ni * 16 + r;
      f32x4 v = acc[mi][ni];
#pragma unroll
      for (int e = 0; e < 4; ++e) {
        int grow = grow0 + e;
        if (MODE == 0) {
          Cf[(size_t)grow * Ncols + gcol] =
              v[e] + residual[(size_t)grow * Ncols + gcol];
        } else {
          int which = gcol >> 10, rem = gcol & 1023, hh = rem >> 6, d = rem & 63;
          Cqkv[((size_t)(which * 16 + hh) * M + grow) * 64 + d] = f2bf(v[e]);
        }
      }
    }
  }
}

// ---------------------------------------------------------------------------
// RoPE in place on Q,K planes of QKV [3][16][N][64] bf16.
// ---------------------------------------------------------------------------
__global__ __launch_bounds__(256) void rope_kernel(
    unsigned short* __restrict__ QKV, const float* __restrict__ pos,
    const float* __restrict__ freqs, int Ntok) {
  int t = blockIdx.x * 256 + threadIdx.x;
  if (t >= Ntok * 512) return;
  int kk = t & 31, h = (t >> 5) & 15, i = t >> 9;
  float lvlf = pos[i * 3 + 0];
  float py   = pos[i * 3 + 1];
  float px   = pos[i * 3 + 2];
  int lvl = (int)lvlf;
  lvl = lvl < 0 ? 0 : (lvl > 3 ? 3 : lvl);
  const float* fp = freqs + (((lvl * 16 + h) * 32 + kk) << 1);
  float ang = fp[0] * py + fp[1] * px;
  float s, c;
  __sincosf(ang, &s, &c);
  size_t qoff = ((size_t)h * Ntok + i) * 64 + 2 * kk;
  size_t koff = qoff + (size_t)16 * Ntok * 64;
  unsigned int q2 = *(const unsigned int*)(QKV + qoff);
  float qa = bf2f((unsigned short)(q2 & 0xffff));
  float qb = bf2f((unsigned short)(q2 >> 16));
  *(unsigned int*)(QKV + qoff) =
      (unsigned int)f2bf(qa * c - qb * s) | ((unsigned int)f2bf(qa * s + qb * c) << 16);
  unsigned int k2 = *(const unsigned int*)(QKV + koff);
  float ka = bf2f((unsigned short)(k2 & 0xffff));
  float kb = bf2f((unsigned short)(k2 >> 16));
  *(unsigned int*)(QKV + koff) =
      (unsigned int)f2bf(ka * c - kb * s) | ((unsigned int)f2bf(ka * s + kb * c) << 16);
}

// ---------------------------------------------------------------------------
// Flash attention.  Block = (batch, head, 64 q rows); 4 waves x 16 q rows.
// S^T = K*Q^T (mfma 16x16x32); per-64-key-tile online softmax (log2 domain,
// defer-max); V transposed in LDS so PV B-frags are ds_read_b64; reg-staged
// single-LDS-buffer pipeline; XCD-aware block swizzle.
// ---------------------------------------------------------------------------
__global__ __launch_bounds__(256) void attn_kernel(
    const unsigned short* __restrict__ QKV, const int* __restrict__ boff,
    unsigned short* __restrict__ O, int Ntok) {
  __shared__ unsigned short Klds[64][72];
  __shared__ unsigned short Vt[64][72];   // Vt[d][key]
  const float SCALE_LOG2 = 0.125f * 1.44269504088896340736f;

  int nb  = gridDim.x;
  int bid = blockIdx.x;
  int cpx = nb >> 3;                       // nb % 8 == 0 (2048)
  int blk = (bid & 7) * cpx + (bid >> 3);  // XCD-contiguous work chunks
  int qblk = blk & 15, h = (blk >> 4) & 15, b = blk >> 8;
  int off = boff[b], len = boff[b + 1] - off;
  int q0 = qblk * 64;
  if (q0 >= len) return;
  int t = threadIdx.x, lane = t & 63, wave = t >> 6;
  int r = lane & 15, g = lane >> 4;
  const unsigned short* Qg = QKV + (size_t)h * Ntok * 64;
  const unsigned short* Kg = QKV + (size_t)(16 + h) * Ntok * 64;
  const unsigned short* Vg = QKV + (size_t)(32 + h) * Ntok * 64;
  int qmax = off + len - 1;

  bf16x8 qf[2];
  {
    int qtok = off + q0 + wave * 16 + r;
    if (qtok > qmax) qtok = qmax;
#pragma unroll
    for (int c = 0; c < 2; ++c)
      qf[c] = *(const bf16x8*)(Qg + (size_t)qtok * 64 + c * 32 + g * 8);
  }

  float m = -1e30f, lsum = 0.f;
  f32x4 o[4] = {};

  // staging assignments
  int krow = t >> 2, kseg = t & 3;   // K: key=krow, d = kseg*16..+15
  int vp = t & 31, vdc = t >> 5;     // V: keys 2vp,2vp+1, d = vdc*8..+7

  s16x8 kr0, kr1, vr0, vr1;
  {
    int ktok = off + krow; if (ktok > qmax) ktok = qmax;
    kr0 = *(const s16x8*)(Kg + (size_t)ktok * 64 + kseg * 16);
    kr1 = *(const s16x8*)(Kg + (size_t)ktok * 64 + kseg * 16 + 8);
    int va = off + 2 * vp, vb = va + 1;
    if (va > qmax) va = qmax;
    if (vb > qmax) vb = qmax;
    vr0 = *(const s16x8*)(Vg + (size_t)va * 64 + vdc * 8);
    vr1 = *(const s16x8*)(Vg + (size_t)vb * 64 + vdc * 8);
  }

  for (int kt = 0; kt < len; kt += 64) {
    __syncthreads();                       // previous tile's compute done
    *(s16x8*)&Klds[krow][kseg * 16]     = kr0;
    *(s16x8*)&Klds[krow][kseg * 16 + 8] = kr1;
#pragma unroll
    for (int j = 0; j < 8; ++j) {
      unsigned int pk = (unsigned int)(unsigned short)vr0[j] |
                        ((unsigned int)(unsigned short)vr1[j] << 16);
      *(unsigned int*)&Vt[vdc * 8 + j][2 * vp] = pk;
    }
    int ktn = kt + 64;
    if (ktn < len) {                       // prefetch next tile into regs
      int ktok = off + ktn + krow; if (ktok > qmax) ktok = qmax;
      kr0 = *(const s16x8*)(Kg + (size_t)ktok * 64 + kseg * 16);
      kr1 = *(const s16x8*)(Kg + (size_t)ktok * 64 + kseg * 16 + 8);
      int va = off + ktn + 2 * vp, vb = va + 1;
      if (va > qmax) va = qmax;
      if (vb > qmax) vb = qmax;
      vr0 = *(const s16x8*)(Vg + (size_t)va * 64 + vdc * 8);
      vr1 = *(const s16x8*)(Vg + (size_t)vb * 64 + vdc * 8);
    }
    __syncthreads();                       // LDS tile ready

    // ---- scores: S^T[key][q] for 64 keys x 16 q rows -------------------
    f32x4 s[4];
#pragma unroll
    for (int sub = 0; sub < 4; ++sub) {
      bf16x8 ka0 = *(const bf16x8*)(&Klds[sub * 16 + r][g * 8]);
      bf16x8 ka1 = *(const bf16x8*)(&Klds[sub * 16 + r][32 + g * 8]);
      f32x4 acc = {};
      acc = mfma32(ka0, qf[0], acc);
      acc = mfma32(ka1, qf[1], acc);
      s[sub] = acc;
    }

    bool tail = (kt + 64 > len);
    s16x4 pf[4];
    {
      float sc[4][4];
      float tmax = -1e30f;
#pragma unroll
      for (int sub = 0; sub < 4; ++sub)
#pragma unroll
        for (int e = 0; e < 4; ++e) {
          float v = s[sub][e] * SCALE_LOG2;
          sc[sub][e] = v;
          tmax = fmaxf(tmax, v);
        }
      if (tail) {
#pragma unroll
        for (int sub = 0; sub < 4; ++sub)
#pragma unroll
          for (int e = 0; e < 4; ++e)
            if (kt + sub * 16 + 4 * g + e >= len) sc[sub][e] = -1e30f;
        tmax = -1e30f;
#pragma unroll
        for (int sub = 0; sub < 4; ++sub)
#pragma unroll
          for (int e = 0; e < 4; ++e) tmax = fmaxf(tmax, sc[sub][e]);
      }
      tmax = fmaxf(tmax, __shfl_xor(tmax, 16));
      tmax = fmaxf(tmax, __shfl_xor(tmax, 32));
      if (!__all(tmax <= m + 8.f)) {       // defer-max (log2 domain)
        float mnew = fmaxf(m, tmax);
        float alpha = exp2f(m - mnew);
        lsum *= alpha;
        m = mnew;
        float al[4];
#pragma unroll
        for (int e = 0; e < 4; ++e) al[e] = __shfl(alpha, 4 * g + e);
#pragma unroll
        for (int dt = 0; dt < 4; ++dt)
#pragma unroll
          for (int e = 0; e < 4; ++e) o[dt][e] *= al[e];
      }
      float psum = 0.f;
#pragma unroll
      for (int sub = 0; sub < 4; ++sub) {
        float p[4];
        bf16x4 pb;
#pragma unroll
        for (int e = 0; e < 4; ++e) {
          p[e] = exp2f(sc[sub][e] - m);
          psum += p[e];
          pb[e] = (__bf16)p[e];
        }
        pf[sub] = __builtin_bit_cast(s16x4, pb);
      }
      psum += __shfl_xor(psum, 16);
      psum += __shfl_xor(psum, 32);
      lsum += psum;
    }

    // ---- PV: O += P * V  (V^T frags are vector b64 reads) ---------------
#pragma unroll
    for (int dt = 0; dt < 4; ++dt)
#pragma unroll
      for (int sub = 0; sub < 4; ++sub) {
        s16x4 vf = *(const s16x4*)(&Vt[dt * 16 + r][sub * 16 + 4 * g]);
        o[dt] = mfma16(pf[sub], vf, o[dt]);
      }
  }

  float inv = 1.0f / lsum;
  float il[4];
#pragma unroll
  for (int e = 0; e < 4; ++e) il[e] = __shfl(inv, 4 * g + e);
#pragma unroll
  for (int dt = 0; dt < 4; ++dt)
#pragma unroll
    for (int e = 0; e < 4; ++e) {
      int tl = q0 + wave * 16 + 4 * g + e;
      if (tl < len)
        O[(size_t)(off + tl) * 1024 + h * 64 + dt * 16 + r] =
            f2bf(o[dt][e] * il[e]);
    }
}

// ---------------------------------------------------------------------------
extern "C" void kernel_launch(void* const* d_in, const int* in_sizes, int n_in,
                              void* d_out, int out_size, void* d_ws, size_t ws_size,
                              hipStream_t stream) {
  const float* x     = (const float*)d_in[0];
  const float* pos   = (const float*)d_in[1];
  const int*   boff  = (const int*)d_in[2];
  const float* gamma = (const float*)d_in[3];
  const float* beta  = (const float*)d_in[4];
  const float* wqkv  = (const float*)d_in[5];
  const float* wout  = (const float*)d_in[6];
  const float* freqs = (const float*)d_in[7];
  float* out = (float*)d_out;
  int N  = in_sizes[0] / 1024;   // 6144
  int Bn = in_sizes[2] - 1;      // 8

  char* ws = (char*)d_ws;
  unsigned short* wqkvT = (unsigned short*)ws;
  unsigned short* woutT = (unsigned short*)(ws + (size_t)3072 * 1024 * 2);
  unsigned short* QKV   = (unsigned short*)(ws + (size_t)3072 * 1024 * 2 +
                                            (size_t)1024 * 1024 * 2);
  size_t qkvBytes = (size_t)48 * N * 64 * 2;
  unsigned short* hbuf = (unsigned short*)((char*)QKV + qkvBytes);
  unsigned short* Obuf = hbuf;  // h is dead after the QKV GEMM

  ln_kernel<<<N / 4, 256, 0, stream>>>(x, gamma, beta, hbuf, N);
  transpose_bf16<<<dim3(3072 / 64, 1024 / 64), 256, 0, stream>>>(wqkv, wqkvT, 1024, 3072);
  transpose_bf16<<<dim3(1024 / 64, 1024 / 64), 256, 0, stream>>>(wout, woutT, 1024, 1024);
  gemm_bt<1><<<dim3(3072 / 128, N / 128), 256, 0, stream>>>(
      hbuf, wqkvT, nullptr, nullptr, QKV, N, 3072, 1024);
  rope_kernel<<<(N * 512) / 256, 256, 0, stream>>>(QKV, pos, freqs, N);
  attn_kernel<<<Bn * 16 * 16, 256, 0, stream>>>(QKV, boff, Obuf, N);
  gemm_bt<0><<<dim3(1024 / 128, N / 128), 256, 0, stream>>>(
      Obuf, woutT, x, out, nullptr, N, 1024, 1024);
}